// Round 4
// baseline (147.239 us; speedup 1.0000x reference)
//
#include <hip/hip_runtime.h>

// CondLaneHead via bf16 MFMA 16x16x32, all 3 layers fused, swizzled LDS.
// 32 instances (4 img x 8), C=64, H=160, W=256, L=40960 px.
//
// Layer1: D[o][p] = sum_k w0[o][k]*x[k][p], K=64, with the rank-3 aug term
//   (b0 + wx*fx + wy*fy) computed in exact fp32 as the MFMA C-operand init.
// Layer2: K=64, C-operand = b1. Layer3: VALU dot(w2, relu) + shfl butterfly.
//
// LDS: rows of 64 shorts (128 B), 16B blocks XOR-swizzled by (row&7) ->
// every access pattern (stage b128 write, B-frag b128 read, h uint2 write,
// h b128 read) distributes exactly evenly over banks (round 3 had 1.07e7
// conflict cycles from 48-dword row stride). 32 KB total -> 4 blocks/CU.
//
// Frag layouts (m89/m120-verified): A[m=lane&15][k=(lane>>4)*8+j],
// B[k=(lane>>4)*8+j][n=lane&15], D[row=(lane>>4)*4+r][col=lane&15].

#define NP 8513
#define HW 40960
#define ISTRIDE 36928
#define OFF_W0 0
#define OFF_W1 8192
#define OFF_B1 16384
#define OFF_W2 20480
#define OFF_B0 24576
#define OFF_WX 28672
#define OFF_WY 32768
#define OFF_B2 36864

typedef __attribute__((ext_vector_type(8))) short bf16x8;
typedef __attribute__((ext_vector_type(4))) float f32x4;

__device__ inline unsigned short f2bf(float f) {
  union { float f; unsigned u; } v; v.f = f;
  unsigned r = v.u + 0x7fffu + ((v.u >> 16) & 1u);   // RNE
  return (unsigned short)(r >> 16);
}

__global__ void condlane_prep(const float* __restrict__ params,
                              char* __restrict__ ws) {
  const int inst = blockIdx.x;
  const float* __restrict__ p = params + inst * NP;
  char* base = ws + inst * ISTRIDE;
  unsigned short* w0o = (unsigned short*)(base + OFF_W0);
  unsigned short* w1o = (unsigned short*)(base + OFF_W1);
  float* b1o = (float*)(base + OFF_B1);
  float* w2o = (float*)(base + OFF_W2);
  float* b0o = (float*)(base + OFF_B0);
  float* wxo = (float*)(base + OFF_WX);
  float* wyo = (float*)(base + OFF_WY);

  // A-frags for w0 (K=64: x-channel part only) and w1.
  // elem e: frag = e>>9 (mt*2+kst), lane = (e>>3)&63, j = e&7
  for (int e = threadIdx.x; e < 4096; e += 1024) {
    const int frag = e >> 9, lane = (e >> 3) & 63, j = e & 7;
    const int mt = frag >> 1, kst = frag & 1;
    const int m = mt * 16 + (lane & 15);
    const int k = kst * 32 + ((lane >> 4) << 3) + j;
    w0o[e] = f2bf(p[m * 66 + 2 + k]);
    w1o[e] = f2bf(p[4224 + m * 64 + k]);
  }
  // C-layout f32x4 frags: row o = mt*16 + (lane>>4)*4 + r
  for (int e = threadIdx.x; e < 1024; e += 1024) {
    const int mt = e >> 8, lane = (e >> 2) & 63, r = e & 3;
    const int o = mt * 16 + ((lane >> 4) << 2) + r;
    b1o[e] = p[8448 + o];
    w2o[e] = p[8320 + o];
    b0o[e] = p[8384 + o];
    wxo[e] = p[o * 66 + 0];
    wyo[e] = p[o * 66 + 1];
  }
  if (threadIdx.x == 0) *(float*)(base + OFF_B2) = p[8512] - 2.19f;
}

__global__ __launch_bounds__(256, 4) void condlane_main(
    const float* __restrict__ x, const char* __restrict__ ws,
    float* __restrict__ out) {
  __shared__ __align__(16) unsigned short xs[128 * 64];   // 16 KB, swizzled
  __shared__ __align__(16) unsigned short hs[4 * 32 * 64]; // 16 KB, per-wave
  const int img = blockIdx.y;
  const int px0 = blockIdx.x * 128;
  const int tid = threadIdx.x, lane = tid & 63, wave = tid >> 6;

  // ---- stage x chunk: 2 threads per pixel, 32 channels each ----
  {
    const int px = tid & 127, half = tid >> 7;
    const float* gx = x + img * 64 * HW + px0 + px;
    unsigned short* row = xs + px * 64;
    const int psw = px & 7;
#pragma unroll
    for (int cb = 0; cb < 4; cb++) {
      const int c = half * 32 + cb * 8;
      union { bf16x8 v; unsigned short s[8]; } u;
#pragma unroll
      for (int j = 0; j < 8; j++) u.s[j] = f2bf(gx[(c + j) * HW]);
      *(bf16x8*)(row + (((c >> 3) ^ psw) << 3)) = u.v;
    }
  }
  __syncthreads();

  const int col = lane & 15, q = lane >> 4, sw = lane & 7;

  // ---- x B-frags to regs once; reused across all 8 instances ----
  bf16x8 bfr[2][2];
#pragma unroll
  for (int nt = 0; nt < 2; nt++)
#pragma unroll
    for (int ks = 0; ks < 2; ks++)
      bfr[nt][ks] = *(const bf16x8*)(xs + (wave * 32 + nt * 16 + col) * 64 +
                                     (((ks * 4 + q) ^ sw) << 3));
  float fx[2], fy[2];
#pragma unroll
  for (int nt = 0; nt < 2; nt++) {
    const int pg = px0 + wave * 32 + nt * 16 + col;
    fx[nt] = (float)(pg & 255);   // loc_x (W=256)
    fy[nt] = (float)(pg >> 8);    // loc_y
  }
  unsigned short* hrow = hs + wave * 32 * 64;
  float* outp = out + px0 + wave * 32;
  const int iid0 = img * 8;

  for (int inst = 0; inst < 8; inst++) {
    const char* wb = ws + (iid0 + inst) * ISTRIDE;
    const bf16x8* w0f = (const bf16x8*)(wb + OFF_W0);
    const bf16x8* w1f = (const bf16x8*)(wb + OFF_W1);
    const f32x4* b1f = (const f32x4*)(wb + OFF_B1);
    const f32x4* w2f = (const f32x4*)(wb + OFF_W2);
    const f32x4* b0f = (const f32x4*)(wb + OFF_B0);
    const f32x4* wxf = (const f32x4*)(wb + OFF_WX);
    const f32x4* wyf = (const f32x4*)(wb + OFF_WY);
    const float b2 = *(const float*)(wb + OFF_B2);

    // ---- layer 1: C-init = b0 + wx*fx + wy*fy (exact fp32), then K=64 MFMA
    f32x4 acc[4][2];
#pragma unroll
    for (int mt = 0; mt < 4; mt++) {
      const f32x4 b0v = b0f[mt * 64 + lane];
      const f32x4 wxv = wxf[mt * 64 + lane];
      const f32x4 wyv = wyf[mt * 64 + lane];
#pragma unroll
      for (int nt = 0; nt < 2; nt++)
        acc[mt][nt] = b0v + wxv * fx[nt] + wyv * fy[nt];
    }
#pragma unroll
    for (int mt = 0; mt < 4; mt++) {
      const bf16x8 a0 = w0f[(mt * 2 + 0) * 64 + lane];
      const bf16x8 a1 = w0f[(mt * 2 + 1) * 64 + lane];
#pragma unroll
      for (int nt = 0; nt < 2; nt++) {
        f32x4 c = __builtin_amdgcn_mfma_f32_16x16x32_bf16(a0, bfr[nt][0],
                                                          acc[mt][nt], 0, 0, 0);
        acc[mt][nt] = __builtin_amdgcn_mfma_f32_16x16x32_bf16(a1, bfr[nt][1],
                                                              c, 0, 0, 0);
      }
    }
    // ---- relu -> bf16 -> wave-local swizzled LDS (C-layout -> B-layout) ----
#pragma unroll
    for (int mt = 0; mt < 4; mt++)
#pragma unroll
      for (int nt = 0; nt < 2; nt++) {
        const f32x4 v = acc[mt][nt];
        uint2 dd;
        dd.x = (unsigned)f2bf(fmaxf(v.x, 0.f)) |
               ((unsigned)f2bf(fmaxf(v.y, 0.f)) << 16);
        dd.y = (unsigned)f2bf(fmaxf(v.z, 0.f)) |
               ((unsigned)f2bf(fmaxf(v.w, 0.f)) << 16);
        const int kb = (mt * 2 + (q >> 1)) ^ sw;
        *(uint2*)(hrow + (nt * 16 + col) * 64 + (kb << 3) + ((q & 1) << 2)) = dd;
      }
    bf16x8 hbf[2][2];   // same-wave RAW: compiler inserts lgkmcnt wait
#pragma unroll
    for (int nt = 0; nt < 2; nt++)
#pragma unroll
      for (int ks = 0; ks < 2; ks++)
        hbf[nt][ks] = *(const bf16x8*)(hrow + (nt * 16 + col) * 64 +
                                       (((ks * 4 + q) ^ sw) << 3));

    // ---- layer 2 (C-operand = b1) ----
    f32x4 acc2[4][2];
#pragma unroll
    for (int mt = 0; mt < 4; mt++) {
      const bf16x8 a0 = w1f[(mt * 2 + 0) * 64 + lane];
      const bf16x8 a1 = w1f[(mt * 2 + 1) * 64 + lane];
      const f32x4 cb = b1f[mt * 64 + lane];
#pragma unroll
      for (int nt = 0; nt < 2; nt++) {
        f32x4 c = __builtin_amdgcn_mfma_f32_16x16x32_bf16(a0, hbf[nt][0],
                                                          cb, 0, 0, 0);
        acc2[mt][nt] = __builtin_amdgcn_mfma_f32_16x16x32_bf16(a1, hbf[nt][1],
                                                               c, 0, 0, 0);
      }
    }
    // ---- layer 3: dot(w2, relu) in VALU + butterfly over row-groups ----
    float s0 = 0.f, s1 = 0.f;
#pragma unroll
    for (int mt = 0; mt < 4; mt++) {
      const f32x4 w2v = w2f[mt * 64 + lane];
      const f32x4 v0 = acc2[mt][0], v1 = acc2[mt][1];
      s0 += w2v.x * fmaxf(v0.x, 0.f); s1 += w2v.x * fmaxf(v1.x, 0.f);
      s0 += w2v.y * fmaxf(v0.y, 0.f); s1 += w2v.y * fmaxf(v1.y, 0.f);
      s0 += w2v.z * fmaxf(v0.z, 0.f); s1 += w2v.z * fmaxf(v1.z, 0.f);
      s0 += w2v.w * fmaxf(v0.w, 0.f); s1 += w2v.w * fmaxf(v1.w, 0.f);
    }
    s0 += __shfl_xor(s0, 16, 64); s0 += __shfl_xor(s0, 32, 64);
    s1 += __shfl_xor(s1, 16, 64); s1 += __shfl_xor(s1, 32, 64);
    if (lane < 32) {
      const int nt = lane >> 4;
      outp[(iid0 + inst) * HW + nt * 16 + col] = (nt ? s1 : s0) + b2;
    }
  }
}

extern "C" void kernel_launch(void* const* d_in, const int* in_sizes, int n_in,
                              void* d_out, int out_size, void* d_ws, size_t ws_size,
                              hipStream_t stream) {
  const float* x      = (const float*)d_in[0];  // [4,64,160,256] fp32
  const float* params = (const float*)d_in[1];  // [32,8513] fp32
  // d_in[2] = num_ins (static 8/img; inst mapping hardcoded)
  float* out = (float*)d_out;

  condlane_prep<<<32, 1024, 0, stream>>>(params, (char*)d_ws);  // 1.18 MB used
  condlane_main<<<dim3(320, 4), 256, 0, stream>>>(x, (const char*)d_ws, out);
}

// Round 5
// 128.008 us; speedup vs baseline: 1.1502x; 1.1502x over previous
//
#include <hip/hip_runtime.h>
#include <hip/hip_bf16.h>

// CondLaneHead via bf16 MFMA 16x16x32, 3 layers fused, software-pipelined.
// 32 instances (4 img x 8), C=64, H=160, W=256, L=40960 px.
//
// Round-4 lesson: kernel was latency-bound on the serial per-instance chain
// (MfmaUtil 10%, VALUBusy 30%). This round double-buffers the per-wave h
// region and pipelines: readH(i) -> layer1(i+1) -> layer2/3(i). DS ops are
// in-order per wave and reads are issued before the next batch of writes, so
// the lgkmcnt wait at readH covers ops issued one full iteration earlier.
//
// Layer1: K=64 MFMA with C-init = b0 + wx*fx + wy*fy in exact fp32
// (fy is block-constant: 128-px chunks never cross an image row).
// Layer2: K=64, C=b1. Layer3: VALU dot + shfl butterfly.
// LDS 16B-block XOR swizzle (round 4) keeps all patterns conflict-free.
//
// Frag layouts (m89/m120-verified): A[m=lane&15][k=(lane>>4)*8+j],
// B[k=(lane>>4)*8+j][n=lane&15], D[row=(lane>>4)*4+r][col=lane&15].

#define NP 8513
#define HW 40960
#define ISTRIDE 36928
#define OFF_W0 0
#define OFF_W1 8192
#define OFF_B1 16384
#define OFF_W2 20480
#define OFF_B0 24576
#define OFF_WX 28672
#define OFF_WY 32768
#define OFF_B2 36864

typedef __attribute__((ext_vector_type(8))) short bf16x8;
typedef __attribute__((ext_vector_type(4))) float f32x4;

__device__ inline unsigned short f2bf(float f) {
  union { float f; unsigned u; } v; v.f = f;
  unsigned r = v.u + 0x7fffu + ((v.u >> 16) & 1u);   // RNE
  return (unsigned short)(r >> 16);
}
__device__ inline unsigned pk2(float a, float b) {   // [lo=a, hi=b] bf16x2
  __hip_bfloat162 h = __float22bfloat162_rn(float2{a, b});
  union { __hip_bfloat162 h; unsigned u; } v; v.h = h;
  return v.u;
}

// 256 blocks x 256 threads: 8 parts per instance (round 4's 32-block prep
// was ~70 us of the 147 total -- uncoalesced reads at 12% CU occupancy).
__global__ void condlane_prep(const float* __restrict__ params,
                              char* __restrict__ ws) {
  const int inst = blockIdx.x >> 3, part = blockIdx.x & 7;
  const float* __restrict__ p = params + inst * NP;
  char* base = ws + inst * ISTRIDE;
  if (part < 4) {  // A-frags: parts 0-1 = w0, 2-3 = w1
    const int isw1 = part >> 1;
    unsigned short* dst = (unsigned short*)(base + (isw1 ? OFF_W1 : OFF_W0));
#pragma unroll
    for (int t = 0; t < 8; t++) {
      const int e = (part & 1) * 2048 + t * 256 + threadIdx.x;
      const int frag = e >> 9, lane = (e >> 3) & 63, j = e & 7;
      const int mt = frag >> 1, kst = frag & 1;
      const int m = mt * 16 + (lane & 15);
      const int k = kst * 32 + ((lane >> 4) << 3) + j;
      dst[e] = f2bf(isw1 ? p[4224 + m * 64 + k] : p[m * 66 + 2 + k]);
    }
  } else if (part == 4) {  // C-layout f32x4 frags (o = mt*16+(lane>>4)*4+r)
    float* b1o = (float*)(base + OFF_B1);
    float* w2o = (float*)(base + OFF_W2);
    float* b0o = (float*)(base + OFF_B0);
    float* wxo = (float*)(base + OFF_WX);
    float* wyo = (float*)(base + OFF_WY);
#pragma unroll
    for (int t = 0; t < 4; t++) {
      const int e = t * 256 + threadIdx.x;
      const int mt = e >> 8, lane = (e >> 2) & 63, r = e & 3;
      const int o = mt * 16 + ((lane >> 4) << 2) + r;
      b1o[e] = p[8448 + o];
      w2o[e] = p[8320 + o];
      b0o[e] = p[8384 + o];
      wxo[e] = p[o * 66 + 0];
      wyo[e] = p[o * 66 + 1];
    }
    if (threadIdx.x == 0) *(float*)(base + OFF_B2) = p[8512] - 2.19f;
  }
}

__global__ __launch_bounds__(256, 3) void condlane_main(
    const float* __restrict__ x, const char* __restrict__ ws,
    float* __restrict__ out) {
  __shared__ __align__(16) unsigned short xs[128 * 64];        // 16 KB
  __shared__ __align__(16) unsigned short hs[4 * 2 * 2048];    // 32 KB dbuf
  const int img = blockIdx.y;
  const int px0 = blockIdx.x * 128;
  const int tid = threadIdx.x, lane = tid & 63, wave = tid >> 6;

  // ---- stage x chunk (swizzled): 2 threads per pixel, 32 channels each ----
  {
    const int px = tid & 127, half = tid >> 7;
    const float* gx = x + img * 64 * HW + px0 + px;
    unsigned short* row = xs + px * 64;
    const int psw = px & 7;
#pragma unroll
    for (int cb = 0; cb < 4; cb++) {
      const int c = half * 32 + cb * 8;
      union { bf16x8 v; unsigned short s[8]; } u;
#pragma unroll
      for (int j = 0; j < 8; j++) u.s[j] = f2bf(gx[(c + j) * HW]);
      *(bf16x8*)(row + (((c >> 3) ^ psw) << 3)) = u.v;
    }
  }
  __syncthreads();

  const int col = lane & 15, q = lane >> 4, sw = lane & 7;

  // x B-frags to regs once; reused across all 8 instances
  bf16x8 bfr[2][2];
#pragma unroll
  for (int nt = 0; nt < 2; nt++)
#pragma unroll
    for (int ks = 0; ks < 2; ks++)
      bfr[nt][ks] = *(const bf16x8*)(xs + (wave * 32 + nt * 16 + col) * 64 +
                                     (((ks * 4 + q) ^ sw) << 3));
  const float fyv = (float)(blockIdx.x >> 1);             // block-constant
  float fx[2];
  fx[0] = (float)((blockIdx.x & 1) * 128 + wave * 32 + col);
  fx[1] = fx[0] + 16.0f;

  unsigned short* const hb0 = hs + wave * 2 * 2048;
  float* outp = out + px0 + wave * 32;
  const int iid0 = img * 8;

  // ---- stage A: layer1 + pack + LDS write for instance iid into buf ----
  auto stageA = [&](int iid, unsigned short* hbase) {
    const char* wb = ws + iid * ISTRIDE;
    const bf16x8* w0f = (const bf16x8*)(wb + OFF_W0);
    const f32x4* b0f = (const f32x4*)(wb + OFF_B0);
    const f32x4* wxf = (const f32x4*)(wb + OFF_WX);
    const f32x4* wyf = (const f32x4*)(wb + OFF_WY);
    f32x4 acc[4][2];
#pragma unroll
    for (int mt = 0; mt < 4; mt++) {
      const f32x4 byv = b0f[mt * 64 + lane] + wyf[mt * 64 + lane] * fyv;
      const f32x4 wxv = wxf[mt * 64 + lane];
      acc[mt][0] = byv + wxv * fx[0];
      acc[mt][1] = byv + wxv * fx[1];
    }
#pragma unroll
    for (int mt = 0; mt < 4; mt++) {
      const bf16x8 a0 = w0f[(mt * 2 + 0) * 64 + lane];
      const bf16x8 a1 = w0f[(mt * 2 + 1) * 64 + lane];
#pragma unroll
      for (int nt = 0; nt < 2; nt++) {
        f32x4 c = __builtin_amdgcn_mfma_f32_16x16x32_bf16(a0, bfr[nt][0],
                                                          acc[mt][nt], 0, 0, 0);
        acc[mt][nt] = __builtin_amdgcn_mfma_f32_16x16x32_bf16(a1, bfr[nt][1],
                                                              c, 0, 0, 0);
      }
    }
#pragma unroll
    for (int mt = 0; mt < 4; mt++)
#pragma unroll
      for (int nt = 0; nt < 2; nt++) {
        const f32x4 v = acc[mt][nt];
        uint2 dd;
        dd.x = pk2(fmaxf(v.x, 0.f), fmaxf(v.y, 0.f));
        dd.y = pk2(fmaxf(v.z, 0.f), fmaxf(v.w, 0.f));
        const int kb = (mt * 2 + (q >> 1)) ^ sw;
        *(uint2*)(hbase + (nt * 16 + col) * 64 + (kb << 3) + ((q & 1) << 2)) = dd;
      }
  };

  auto readH = [&](unsigned short* hbase, bf16x8 (&hbf)[2][2]) {
#pragma unroll
    for (int nt = 0; nt < 2; nt++)
#pragma unroll
      for (int ks = 0; ks < 2; ks++)
        hbf[nt][ks] = *(const bf16x8*)(hbase + (nt * 16 + col) * 64 +
                                       (((ks * 4 + q) ^ sw) << 3));
  };

  // ---- stage B rest: layer2 MFMA + layer3 dot + store for instance iid ----
  auto stageB = [&](int iid, bf16x8 (&hbf)[2][2]) {
    const char* wb = ws + iid * ISTRIDE;
    const bf16x8* w1f = (const bf16x8*)(wb + OFF_W1);
    const f32x4* b1f = (const f32x4*)(wb + OFF_B1);
    const f32x4* w2f = (const f32x4*)(wb + OFF_W2);
    const float b2 = *(const float*)(wb + OFF_B2);
    float s0 = 0.f, s1 = 0.f;
#pragma unroll
    for (int mt = 0; mt < 4; mt++) {
      const bf16x8 a0 = w1f[(mt * 2 + 0) * 64 + lane];
      const bf16x8 a1 = w1f[(mt * 2 + 1) * 64 + lane];
      const f32x4 cb = b1f[mt * 64 + lane];
      f32x4 c0 = __builtin_amdgcn_mfma_f32_16x16x32_bf16(a0, hbf[0][0], cb, 0, 0, 0);
      const f32x4 v0 = __builtin_amdgcn_mfma_f32_16x16x32_bf16(a1, hbf[0][1], c0, 0, 0, 0);
      f32x4 c1 = __builtin_amdgcn_mfma_f32_16x16x32_bf16(a0, hbf[1][0], cb, 0, 0, 0);
      const f32x4 v1 = __builtin_amdgcn_mfma_f32_16x16x32_bf16(a1, hbf[1][1], c1, 0, 0, 0);
      const f32x4 w2v = w2f[mt * 64 + lane];
      s0 += w2v.x * fmaxf(v0.x, 0.f) + w2v.y * fmaxf(v0.y, 0.f) +
            w2v.z * fmaxf(v0.z, 0.f) + w2v.w * fmaxf(v0.w, 0.f);
      s1 += w2v.x * fmaxf(v1.x, 0.f) + w2v.y * fmaxf(v1.y, 0.f) +
            w2v.z * fmaxf(v1.z, 0.f) + w2v.w * fmaxf(v1.w, 0.f);
    }
    s0 += __shfl_xor(s0, 16, 64); s0 += __shfl_xor(s0, 32, 64);
    s1 += __shfl_xor(s1, 16, 64); s1 += __shfl_xor(s1, 32, 64);
    if (lane < 32) {
      const int nt = lane >> 4;
      outp[iid * HW + nt * 16 + col] = (nt ? s1 : s0) + b2;
    }
  };

  // ---- pipelined instance loop ----
  stageA(iid0 + 0, hb0);
  for (int i = 0; i < 7; i++) {
    bf16x8 hbf[2][2];
    readH(hb0 + (i & 1) * 2048, hbf);        // waits on writes from iter i-1
    stageA(iid0 + i + 1, hb0 + ((i + 1) & 1) * 2048);  // independent filler
    stageB(iid0 + i, hbf);
  }
  {
    bf16x8 hbf[2][2];
    readH(hb0 + (7 & 1) * 2048, hbf);
    stageB(iid0 + 7, hbf);
  }
}

extern "C" void kernel_launch(void* const* d_in, const int* in_sizes, int n_in,
                              void* d_out, int out_size, void* d_ws, size_t ws_size,
                              hipStream_t stream) {
  const float* x      = (const float*)d_in[0];  // [4,64,160,256] fp32
  const float* params = (const float*)d_in[1];  // [32,8513] fp32
  // d_in[2] = num_ins (static 8/img; inst mapping hardcoded)
  float* out = (float*)d_out;

  condlane_prep<<<256, 256, 0, stream>>>(params, (char*)d_ws);  // 1.18 MB used
  condlane_main<<<dim3(320, 4), 256, 0, stream>>>(x, (const char*)d_ws, out);
}